// Round 1
// baseline (205.314 us; speedup 1.0000x reference)
//
#include <hip/hip_runtime.h>

typedef unsigned short u16;
typedef unsigned int   u32;

typedef __attribute__((ext_vector_type(8))) short bf16x8;
typedef __attribute__((ext_vector_type(4))) float f32x4;

#define BB 4
#define MM 2048
#define NN 16384
#define DD 64

__device__ __forceinline__ u16 f2bf(float f) {
    union { float f; u32 u; } v; v.f = f;
    u32 r = v.u + 0x7fffu + ((v.u >> 16) & 1u);   // RNE, no NaN inputs here
    return (u16)(r >> 16);
}

__device__ __forceinline__ bf16x8 pack8(float4 p, float4 q) {
    bf16x8 v;
    v[0] = (short)f2bf(p.x); v[1] = (short)f2bf(p.y);
    v[2] = (short)f2bf(p.z); v[3] = (short)f2bf(p.w);
    v[4] = (short)f2bf(q.x); v[5] = (short)f2bf(q.y);
    v[6] = (short)f2bf(q.z); v[7] = (short)f2bf(q.w);
    return v;
}

// ---------------------------------------------------------------------------
// Kernel 1: inverse-distance interpolation, online-normalized (flash-style).
// Tile: 128 n-rows x 64 d, K-chunks of 64 m. r computed fp32 -> bf16 -> LDS,
// feat chunk transposed to [d][m] bf16 in LDS, 16x16x32 bf16 MFMA, fp32 acc.
// ---------------------------------------------------------------------------
#define TN 128
#define BM 64
#define RS 72   // rbuf row stride in bf16 (64+8 pad; 144B = 16B-aligned)
#define FS 72

__global__ __launch_bounds__(256, 3)
void interp_kernel(const float* __restrict__ xyz_down,
                   const float* __restrict__ xyz_up,
                   const float* __restrict__ feat_down,
                   u16* __restrict__ interp_out)
{
    __shared__ u16   rbuf[TN * RS];     // r (n x m) bf16, A-operand layout
    __shared__ u16   ftbuf[DD * FS];    // feat^T (d x m) bf16, B-operand layout
    __shared__ float xyzb[BM * 3];
    __shared__ float denp[TN * 2];
    __shared__ float invden[TN];

    const int tid = threadIdx.x;
    const int b  = blockIdx.x >> 7;            // NN/TN = 128 blocks per batch
    const int n0 = (blockIdx.x & 127) * TN;

    // r-phase identity: 2 threads per n-row, 32 m's each
    const int nl_r = tid >> 1;
    const int half = tid & 1;
    const float* xu = xyz_up + (size_t)(b * NN + n0 + nl_r) * 3;
    const float ax = xu[0], ay = xu[1], az = xu[2];

    denp[tid] = 0.f;

    const int wave = tid >> 6;
    const int lane = tid & 63;
    const int q    = lane >> 4;
    const int nl   = lane & 15;

    f32x4 acc[2][4];
#pragma unroll
    for (int i = 0; i < 2; i++)
#pragma unroll
        for (int j = 0; j < 4; j++) acc[i][j] = (f32x4){0.f, 0.f, 0.f, 0.f};

    // feat staging identity: thread handles m-pair (sm, sm+1), 8 d's
    const int sm = (tid & 31) * 2;
    const int sd = (tid >> 5) * 8;

    for (int mc = 0; mc < MM; mc += BM) {
        __syncthreads();   // previous chunk's MFMA done; safe to overwrite LDS

        if (tid < 192) xyzb[tid] = xyz_down[(size_t)(b * MM + mc) * 3 + tid];

        {   // stage feat chunk transposed: [d][m] bf16, packed m-pairs
            const float4* f0 = (const float4*)(feat_down + (size_t)(b * MM + mc + sm) * DD + sd);
            const float4* f1 = (const float4*)(feat_down + (size_t)(b * MM + mc + sm + 1) * DD + sd);
            float4 a0 = f0[0], a1 = f0[1];
            float4 b0 = f1[0], b1 = f1[1];
            float r0[8] = {a0.x, a0.y, a0.z, a0.w, a1.x, a1.y, a1.z, a1.w};
            float r1[8] = {b0.x, b0.y, b0.z, b0.w, b1.x, b1.y, b1.z, b1.w};
#pragma unroll
            for (int j = 0; j < 8; j++) {
                u32 pk = (u32)f2bf(r0[j]) | ((u32)f2bf(r1[j]) << 16);
                *(u32*)&ftbuf[(sd + j) * FS + sm] = pk;
            }
        }
        __syncthreads();   // xyzb + ftbuf ready

        {   // r-phase: 32 pairs/thread, fp32 dist + rcp, bf16 pack, b128 writes
            float dl = 0.f;
#pragma unroll
            for (int s = 0; s < 4; s++) {
                bf16x8 v;
#pragma unroll
                for (int j = 0; j < 8; j++) {
                    int m = half * 32 + s * 8 + j;
                    float dx = ax - xyzb[3 * m + 0];
                    float dy = ay - xyzb[3 * m + 1];
                    float dz = az - xyzb[3 * m + 2];
                    float d = fmaf(dx, dx, fmaf(dy, dy, dz * dz)) + 1e-8f;
                    float r = __builtin_amdgcn_rcpf(d);
                    dl += r;
                    v[j] = (short)f2bf(r);
                }
                *(bf16x8*)&rbuf[nl_r * RS + half * 32 + s * 8] = v;
            }
            denp[nl_r * 2 + half] += dl;
        }
        __syncthreads();   // rbuf ready

        {   // MFMA: wave w owns rows [32w,32w+32), all 4 d-tiles
            const int rowbase = wave * 32;
#pragma unroll
            for (int k0 = 0; k0 < BM; k0 += 32) {
                bf16x8 a0 = *(bf16x8*)&rbuf[(rowbase + nl) * RS + k0 + q * 8];
                bf16x8 a1 = *(bf16x8*)&rbuf[(rowbase + 16 + nl) * RS + k0 + q * 8];
#pragma unroll
                for (int dt = 0; dt < 4; dt++) {
                    bf16x8 bb = *(bf16x8*)&ftbuf[(dt * 16 + nl) * FS + k0 + q * 8];
                    acc[0][dt] = __builtin_amdgcn_mfma_f32_16x16x32_bf16(a0, bb, acc[0][dt], 0, 0, 0);
                    acc[1][dt] = __builtin_amdgcn_mfma_f32_16x16x32_bf16(a1, bb, acc[1][dt], 0, 0, 0);
                }
            }
        }
    }

    __syncthreads();
    if (tid < TN) invden[tid] = 1.0f / (denp[tid * 2] + denp[tid * 2 + 1]);
    __syncthreads();

    {   // epilogue: scale by 1/den, store bf16 to workspace
        const int rowbase = wave * 32;
#pragma unroll
        for (int nt = 0; nt < 2; nt++) {
#pragma unroll
            for (int reg = 0; reg < 4; reg++) {
                int nloc = rowbase + nt * 16 + q * 4 + reg;
                float inv = invden[nloc];
                size_t gbase = (size_t)(b * NN + n0 + nloc) * DD;
#pragma unroll
                for (int dt = 0; dt < 4; dt++) {
                    interp_out[gbase + dt * 16 + nl] = f2bf(acc[nt][dt][reg] * inv);
                }
            }
        }
    }
}

// ---------------------------------------------------------------------------
// Kernel 2: fused pointwise MLP: x=[feat_up|interp] (128) -> W1+BN1+ReLU (128)
// -> W2+BN2 (64). 64 n-rows per block, bf16 MFMA, BN folded to scale/shift.
// ---------------------------------------------------------------------------
#define T2 64

__global__ __launch_bounds__(256, 1)
void mlp_kernel(const float* __restrict__ feat_up,
                const u16*   __restrict__ interp,
                const float* __restrict__ W1, const float* __restrict__ b1,
                const float* __restrict__ g1, const float* __restrict__ be1,
                const float* __restrict__ m1, const float* __restrict__ v1,
                const float* __restrict__ W2, const float* __restrict__ b2,
                const float* __restrict__ g2, const float* __restrict__ be2,
                const float* __restrict__ m2, const float* __restrict__ v2,
                float* __restrict__ out)
{
    __shared__ u16 xb[T2 * 136];     // x tile (n x 128) bf16
    __shared__ u16 hb[T2 * 136];     // hidden tile
    __shared__ u16 w1b[128 * 136];   // W1 (o x c) bf16
    __shared__ u16 w2b[64 * 136];    // W2 (o x c) bf16
    __shared__ float A1[128], Bc1[128], A2[64], Bc2[64];

    const int tid = threadIdx.x;
    const int b  = blockIdx.x >> 8;            // NN/T2 = 256 blocks per batch
    const int n0 = (blockIdx.x & 255) * T2;

    const int wave = tid >> 6;
    const int lane = tid & 63;
    const int q    = lane >> 4;
    const int nl   = lane & 15;

    // fold BN into per-channel scale/shift
    if (tid < 128) {
        float a = g1[tid] * rsqrtf(v1[tid] + 1e-5f);
        A1[tid]  = a;
        Bc1[tid] = (b1[tid] - m1[tid]) * a + be1[tid];
    } else if (tid < 192) {
        int o = tid - 128;
        float a = g2[o] * rsqrtf(v2[o] + 1e-5f);
        A2[o]  = a;
        Bc2[o] = (b2[o] - m2[o]) * a + be2[o];
    }

    {   // stage W1 -> bf16 LDS: thread (o=tid>>1, half=tid&1), 64 floats
        const float4* src = (const float4*)(W1 + (size_t)(tid >> 1) * 128 + (tid & 1) * 64);
        u16* dst = &w1b[(tid >> 1) * 136 + (tid & 1) * 64];
#pragma unroll
        for (int i = 0; i < 8; i++)
            *(bf16x8*)(dst + 8 * i) = pack8(src[2 * i], src[2 * i + 1]);
    }
    {   // stage W2: thread (o=tid>>2, seg=tid&3), 32 floats
        const float4* src = (const float4*)(W2 + (size_t)(tid >> 2) * 128 + (tid & 3) * 32);
        u16* dst = &w2b[(tid >> 2) * 136 + (tid & 3) * 32];
#pragma unroll
        for (int i = 0; i < 4; i++)
            *(bf16x8*)(dst + 8 * i) = pack8(src[2 * i], src[2 * i + 1]);
    }
    // stage x tile: waves 0-1: feat_up fp32->bf16 (c 0..63); waves 2-3: interp bf16 copy (c 64..127)
    if (tid < 128) {
        int n = tid >> 1, hf = tid & 1;
        const float4* src = (const float4*)(feat_up + (size_t)(b * NN + n0 + n) * 64 + hf * 32);
        u16* dst = &xb[n * 136 + hf * 32];
#pragma unroll
        for (int i = 0; i < 4; i++)
            *(bf16x8*)(dst + 8 * i) = pack8(src[2 * i], src[2 * i + 1]);
    } else {
        int t2 = tid - 128;
        int n = t2 >> 1, hf = t2 & 1;
        const uint4* src = (const uint4*)(interp + (size_t)(b * NN + n0 + n) * 64 + hf * 32);
        u16* dst = &xb[n * 136 + 64 + hf * 32];
#pragma unroll
        for (int i = 0; i < 4; i++)
            *(uint4*)(dst + 8 * i) = src[i];
    }
    __syncthreads();

    // GEMM1: (64x128)x(128->128). wave w owns n-tile w, 8 o-tiles.
    f32x4 acc1[8];
#pragma unroll
    for (int i = 0; i < 8; i++) acc1[i] = (f32x4){0.f, 0.f, 0.f, 0.f};
#pragma unroll
    for (int k0 = 0; k0 < 128; k0 += 32) {
        bf16x8 a = *(bf16x8*)&xb[(wave * 16 + nl) * 136 + k0 + q * 8];
#pragma unroll
        for (int ot = 0; ot < 8; ot++) {
            bf16x8 bb = *(bf16x8*)&w1b[(ot * 16 + nl) * 136 + k0 + q * 8];
            acc1[ot] = __builtin_amdgcn_mfma_f32_16x16x32_bf16(a, bb, acc1[ot], 0, 0, 0);
        }
    }
    // epilogue1: BN1 + ReLU -> bf16 hidden
#pragma unroll
    for (int ot = 0; ot < 8; ot++) {
        int o = ot * 16 + nl;
        float aa = A1[o], bc = Bc1[o];
#pragma unroll
        for (int reg = 0; reg < 4; reg++) {
            float v = fmaxf(fmaf(acc1[ot][reg], aa, bc), 0.f);
            hb[(wave * 16 + q * 4 + reg) * 136 + o] = f2bf(v);
        }
    }
    __syncthreads();

    // GEMM2: (64x128)x(128->64). wave w owns n-tile w, 4 o-tiles.
    f32x4 acc2[4];
#pragma unroll
    for (int i = 0; i < 4; i++) acc2[i] = (f32x4){0.f, 0.f, 0.f, 0.f};
#pragma unroll
    for (int k0 = 0; k0 < 128; k0 += 32) {
        bf16x8 a = *(bf16x8*)&hb[(wave * 16 + nl) * 136 + k0 + q * 8];
#pragma unroll
        for (int ot = 0; ot < 4; ot++) {
            bf16x8 bb = *(bf16x8*)&w2b[(ot * 16 + nl) * 136 + k0 + q * 8];
            acc2[ot] = __builtin_amdgcn_mfma_f32_16x16x32_bf16(a, bb, acc2[ot], 0, 0, 0);
        }
    }
    // epilogue2: BN2 -> fp32 out
#pragma unroll
    for (int ot = 0; ot < 4; ot++) {
        int o = ot * 16 + nl;
        float aa = A2[o], bc = Bc2[o];
#pragma unroll
        for (int reg = 0; reg < 4; reg++) {
            out[(size_t)(b * NN + n0 + wave * 16 + q * 4 + reg) * 64 + o] =
                fmaf(acc2[ot][reg], aa, bc);
        }
    }
}

extern "C" void kernel_launch(void* const* d_in, const int* in_sizes, int n_in,
                              void* d_out, int out_size, void* d_ws, size_t ws_size,
                              hipStream_t stream) {
    const float* xyz_down  = (const float*)d_in[0];
    const float* xyz_up    = (const float*)d_in[1];
    const float* feat_down = (const float*)d_in[2];
    const float* feat_up   = (const float*)d_in[3];
    const float* W1  = (const float*)d_in[4];
    const float* b1  = (const float*)d_in[5];
    const float* g1  = (const float*)d_in[6];
    const float* be1 = (const float*)d_in[7];
    const float* m1  = (const float*)d_in[8];
    const float* v1  = (const float*)d_in[9];
    const float* W2  = (const float*)d_in[10];
    const float* b2  = (const float*)d_in[11];
    const float* g2  = (const float*)d_in[12];
    const float* be2 = (const float*)d_in[13];
    const float* m2  = (const float*)d_in[14];
    const float* v2  = (const float*)d_in[15];
    float* out = (float*)d_out;
    u16* interp = (u16*)d_ws;   // B*N*64 bf16 = 8 MB scratch

    interp_kernel<<<dim3(BB * (NN / TN)), dim3(256), 0, stream>>>(
        xyz_down, xyz_up, feat_down, interp);
    mlp_kernel<<<dim3(BB * (NN / T2)), dim3(256), 0, stream>>>(
        feat_up, interp, W1, b1, g1, be1, m1, v1,
        W2, b2, g2, be2, m2, v2, out);
}

// Round 3
// 194.391 us; speedup vs baseline: 1.0562x; 1.0562x over previous
//
#include <hip/hip_runtime.h>

typedef unsigned short u16;
typedef unsigned int   u32;

typedef __attribute__((ext_vector_type(8))) short bf16x8;
typedef __attribute__((ext_vector_type(4))) float f32x4;

#define BB 4
#define MM 2048
#define NN 16384
#define DD 64

__device__ __forceinline__ u16 f2bf(float f) {
    union { float f; u32 u; } v; v.f = f;
    u32 r = v.u + 0x7fffu + ((v.u >> 16) & 1u);   // RNE
    return (u16)(r >> 16);
}

// pack two floats to bf16 pair by truncation: lo16=trunc(lo), hi16=trunc(hi)
__device__ __forceinline__ u32 pack_trunc(float hi, float lo) {
    union { float f; u32 u; } a, b; a.f = hi; b.f = lo;
    return __builtin_amdgcn_perm(a.u, b.u, 0x07060302);
}

// RNE pack of two floats into a bf16 pair
__device__ __forceinline__ u32 pack_rne(float hi, float lo) {
    return (u32)f2bf(lo) | ((u32)f2bf(hi) << 16);
}

__device__ __forceinline__ bf16x8 pack8(float4 p, float4 q) {
    bf16x8 v;
    v[0] = (short)f2bf(p.x); v[1] = (short)f2bf(p.y);
    v[2] = (short)f2bf(p.z); v[3] = (short)f2bf(p.w);
    v[4] = (short)f2bf(q.x); v[5] = (short)f2bf(q.y);
    v[6] = (short)f2bf(q.z); v[7] = (short)f2bf(q.w);
    return v;
}

// ===========================================================================
// ws layout (v2 path):
//   [0, 8M)        interp bf16 [b][n][64]
//   [8M, 9M)       fdT   bf16 [b][d][m]   (feat_down transposed)
//   [9M, +128K)    xyzd2 float4 [b*M]  = (-2bx,-2by,-2bz, |b|^2+1e-8)
//   [.., +32K)     W1 bf16 [128][128]
//   [.., +16K)     W2 bf16 [64][128]
//   [.., +1.5K)    bn consts float[384] = A1[128] Bc1[128] A2[64] Bc2[64]
// ===========================================================================
#define OFF_INTERP 0ull
#define OFF_FDT    8388608ull
#define OFF_XYZ    9437184ull
#define OFF_W1     9568256ull
#define OFF_W2     9601024ull
#define OFF_BN     9617408ull
#define WS_NEED    9618944ull

// ---------------------------------------------------------------------------
// prep: weight/feature conversion + BN fold. 67 blocks x 256.
// ---------------------------------------------------------------------------
__global__ void prep_kernel(const float* __restrict__ xyz_down,
                            const float* __restrict__ feat_down,
                            const float* __restrict__ W1, const float* __restrict__ b1,
                            const float* __restrict__ g1, const float* __restrict__ be1,
                            const float* __restrict__ m1, const float* __restrict__ v1,
                            const float* __restrict__ W2, const float* __restrict__ b2,
                            const float* __restrict__ g2, const float* __restrict__ be2,
                            const float* __restrict__ m2, const float* __restrict__ v2,
                            u16* __restrict__ fdT, float4* __restrict__ xyzd2,
                            u16* __restrict__ w1bf, u16* __restrict__ w2bf,
                            float* __restrict__ bnbuf)
{
    const int blk = blockIdx.x, t = threadIdx.x;
    if (blk < 32) {
        // feat_down transpose: [b][m][64] fp32 -> [b][d][m] bf16
        const int b = blk >> 3;
        const int seg = (blk & 7) * 4 + (t >> 6);   // 32 m-segments of 64
        const int d = t & 63;
        u16 tmp[8];
#pragma unroll 2
        for (int i = 0; i < 64; i++) {
            int m = seg * 64 + i;
            tmp[i & 7] = f2bf(feat_down[((size_t)(b * MM + m)) * 64 + d]);
            if ((i & 7) == 7)
                *(uint4*)&fdT[((size_t)(b * 64 + d)) * MM + seg * 64 + i - 7] = *(uint4*)tmp;
        }
    } else if (blk < 64) {
        int idx = (blk - 32) * 256 + t;             // b*M + m
        float x = xyz_down[idx * 3 + 0], y = xyz_down[idx * 3 + 1], z = xyz_down[idx * 3 + 2];
        xyzd2[idx] = make_float4(-2.f * x, -2.f * y, -2.f * z,
                                 x * x + y * y + z * z + 1e-8f);
    } else if (blk == 64) {
#pragma unroll
        for (int it = 0; it < 8; it++) {
            int g = it * 256 + t;                   // group of 8 elems
            const float4* s = (const float4*)(W1 + g * 8);
            bf16x8 v = pack8(s[0], s[1]);
            *(bf16x8*)&w1bf[g * 8] = v;
        }
    } else if (blk == 65) {
#pragma unroll
        for (int it = 0; it < 4; it++) {
            int g = it * 256 + t;
            const float4* s = (const float4*)(W2 + g * 8);
            bf16x8 v = pack8(s[0], s[1]);
            *(bf16x8*)&w2bf[g * 8] = v;
        }
    } else {
        if (t < 128) {
            float a = g1[t] * rsqrtf(v1[t] + 1e-5f);
            bnbuf[t] = a;
            bnbuf[128 + t] = (b1[t] - m1[t]) * a + be1[t];
        } else if (t < 192) {
            int o = t - 128;
            float a = g2[o] * rsqrtf(v2[o] + 1e-5f);
            bnbuf[256 + o] = a;
            bnbuf[320 + o] = (b2[o] - m2[o]) * a + be2[o];
        }
    }
}

// ---------------------------------------------------------------------------
// interp v2: TN=64, 1024 blocks. r computed in registers in A-frag order;
// only feat^T chunk + xyzd2 chunk go through LDS. Consistent-den truncation.
// ---------------------------------------------------------------------------
__global__ __launch_bounds__(256, 4)
void interp2_kernel(const float* __restrict__ xyz_up,
                    const u16* __restrict__ fdT,
                    const float4* __restrict__ xyzd2,
                    u16* __restrict__ interp_out)
{
    __shared__ u16    ftbuf[64 * 72];    // feat^T chunk [d][m], stride 72
    __shared__ float4 xyzb[71];          // swizzled: idx = m + (m>>3)
    __shared__ float  invden[64];

    const int tid = threadIdx.x;
    const int b  = blockIdx.x >> 8;
    const int n0 = (blockIdx.x & 255) * 64;
    const int wave = tid >> 6;
    const int lane = tid & 63;
    const int q    = lane >> 4;
    const int nl   = lane & 15;

    const int row = n0 + wave * 16 + nl;
    const float* xu = xyz_up + ((size_t)(b * NN + row)) * 3;
    const float ax = xu[0], ay = xu[1], az = xu[2];
    const float a2 = ax * ax + ay * ay + az * az;

    f32x4 acc[4];
#pragma unroll
    for (int i = 0; i < 4; i++) acc[i] = (f32x4){0.f, 0.f, 0.f, 0.f};
    float dl = 0.f;

    // staging identity: thread covers (d = tid>>2, 32B of m)
    const int sd = tid >> 2, sms = (tid & 3) * 16;
    const u16* fsrc = fdT + ((size_t)(b * 64 + sd)) * MM + sms;
    u16* fdst = &ftbuf[sd * 72 + sms];

    for (int mc = 0; mc < MM; mc += 64) {
        __syncthreads();
        *(uint4*)fdst       = *(const uint4*)(fsrc + mc);
        *(uint4*)(fdst + 8) = *(const uint4*)(fsrc + mc + 8);
        if (tid < 64) xyzb[tid + (tid >> 3)] = xyzd2[b * MM + mc + tid];
        __syncthreads();

#pragma unroll
        for (int k0 = 0; k0 < 64; k0 += 32) {
            u32 fr[4];
#pragma unroll
            for (int jp = 0; jp < 4; jp++) {
                int m0 = k0 + q * 8 + jp * 2;
                int m1 = m0 + 1;
                float4 p0 = *(const float4*)&xyzb[m0 + (m0 >> 3)];
                float4 p1 = *(const float4*)&xyzb[m1 + (m1 >> 3)];
                float d0 = fmaf(p0.x, ax, fmaf(p0.y, ay, fmaf(p0.z, az, p0.w + a2)));
                float d1 = fmaf(p1.x, ax, fmaf(p1.y, ay, fmaf(p1.z, az, p1.w + a2)));
                d0 = fmaxf(d0, 1e-8f);            // guard fp32 cancellation
                d1 = fmaxf(d1, 1e-8f);
                float r0 = __builtin_amdgcn_rcpf(d0);
                float r1 = __builtin_amdgcn_rcpf(d1);
                u32 pk = pack_trunc(r1, r0);
                fr[jp] = pk;
                // denominator from the QUANTIZED r -> num/den bias cancels
                union { u32 u; float f; } lo, hi;
                lo.u = pk << 16; hi.u = pk & 0xffff0000u;
                dl += lo.f + hi.f;
            }
            union { u32 u[4]; bf16x8 v; } af;
            af.u[0] = fr[0]; af.u[1] = fr[1]; af.u[2] = fr[2]; af.u[3] = fr[3];
#pragma unroll
            for (int dt = 0; dt < 4; dt++) {
                bf16x8 bb = *(bf16x8*)&ftbuf[(dt * 16 + nl) * 72 + k0 + q * 8];
                acc[dt] = __builtin_amdgcn_mfma_f32_16x16x32_bf16(af.v, bb, acc[dt], 0, 0, 0);
            }
        }
    }

    // reduce den across the 4 q-lanes holding the same row
    dl += __shfl_xor(dl, 16, 64);
    dl += __shfl_xor(dl, 32, 64);
    if (lane < 16) invden[wave * 16 + nl] = 1.0f / dl;
    __syncthreads();

#pragma unroll
    for (int reg = 0; reg < 4; reg++) {
        int r = wave * 16 + q * 4 + reg;
        float inv = invden[r];
        size_t gbase = ((size_t)(b * NN + n0 + r)) * 64;
#pragma unroll
        for (int dt = 0; dt < 4; dt++)
            interp_out[gbase + dt * 16 + nl] = f2bf(acc[dt][reg] * inv);
    }
}

// ---------------------------------------------------------------------------
// mlp v2: weights & interp read straight from global (bf16, L1/L2-resident);
// only the GEMM1->GEMM2 transpose uses LDS. 64 rows/block, 1024 blocks.
// ---------------------------------------------------------------------------
__global__ __launch_bounds__(256, 4)
void mlp2_kernel(const float* __restrict__ feat_up,
                 const u16* __restrict__ interp,
                 const u16* __restrict__ w1bf,
                 const u16* __restrict__ w2bf,
                 const float* __restrict__ bnbuf,
                 float* __restrict__ out)
{
    __shared__ u16   hb[64 * 136];
    __shared__ float bnl[384];

    const int tid = threadIdx.x;
    const int b  = blockIdx.x >> 8;
    const int n0 = (blockIdx.x & 255) * 64;
    const int wave = tid >> 6;
    const int lane = tid & 63;
    const int q    = lane >> 4;
    const int nl   = lane & 15;

    // FIX(round 2 bug): blockDim=256 but bnl has 384 entries — previous code
    // `if (tid<384) bnl[tid]=...` left bnl[256..383] (A2/Bc2) uninitialized.
    bnl[tid] = bnbuf[tid];
    if (tid < 128) bnl[256 + tid] = bnbuf[256 + tid];

    const int row = n0 + wave * 16 + nl;
    const float* fu = feat_up + ((size_t)(b * NN + row)) * 64;
    const u16*   ip = interp  + ((size_t)(b * NN + row)) * 64;

    f32x4 acc1[8];
#pragma unroll
    for (int i = 0; i < 8; i++) acc1[i] = (f32x4){0.f, 0.f, 0.f, 0.f};
    __syncthreads();

#pragma unroll
    for (int k0 = 0; k0 < 128; k0 += 32) {
        bf16x8 af;
        if (k0 < 64) {
            float4 f0 = *(const float4*)(fu + k0 + q * 8);
            float4 f1 = *(const float4*)(fu + k0 + q * 8 + 4);
            union { u32 u[4]; bf16x8 v; } uu;
            uu.u[0] = pack_rne(f0.y, f0.x);
            uu.u[1] = pack_rne(f0.w, f0.z);
            uu.u[2] = pack_rne(f1.y, f1.x);
            uu.u[3] = pack_rne(f1.w, f1.z);
            af = uu.v;
        } else {
            af = *(const bf16x8*)(ip + (k0 - 64) + q * 8);
        }
#pragma unroll
        for (int ot = 0; ot < 8; ot++) {
            bf16x8 bf = *(const bf16x8*)(w1bf + (ot * 16 + nl) * 128 + k0 + q * 8);
            acc1[ot] = __builtin_amdgcn_mfma_f32_16x16x32_bf16(af, bf, acc1[ot], 0, 0, 0);
        }
    }
    // BN1 + ReLU -> bf16 hidden in LDS (transpose to A-layout)
#pragma unroll
    for (int ot = 0; ot < 8; ot++) {
        int o = ot * 16 + nl;
        float aa = bnl[o], bc = bnl[128 + o];
#pragma unroll
        for (int reg = 0; reg < 4; reg++) {
            float v = fmaxf(fmaf(acc1[ot][reg], aa, bc), 0.f);
            hb[(wave * 16 + q * 4 + reg) * 136 + o] = f2bf(v);
        }
    }
    __syncthreads();

    f32x4 acc2[4];
#pragma unroll
    for (int i = 0; i < 4; i++) acc2[i] = (f32x4){0.f, 0.f, 0.f, 0.f};
#pragma unroll
    for (int k0 = 0; k0 < 128; k0 += 32) {
        bf16x8 af = *(bf16x8*)&hb[(wave * 16 + nl) * 136 + k0 + q * 8];
#pragma unroll
        for (int ot = 0; ot < 4; ot++) {
            bf16x8 bf = *(const bf16x8*)(w2bf + (ot * 16 + nl) * 128 + k0 + q * 8);
            acc2[ot] = __builtin_amdgcn_mfma_f32_16x16x32_bf16(af, bf, acc2[ot], 0, 0, 0);
        }
    }
#pragma unroll
    for (int ot = 0; ot < 4; ot++) {
        int o = ot * 16 + nl;
        float aa = bnl[256 + o], bc = bnl[320 + o];
#pragma unroll
        for (int reg = 0; reg < 4; reg++)
            out[((size_t)(b * NN + n0 + wave * 16 + q * 4 + reg)) * 64 + o] =
                fmaf(acc2[ot][reg], aa, bc);
    }
}

// ===========================================================================
// Fallback (round-1 kernels, proven): used when ws_size < WS_NEED.
// ===========================================================================
#define TN 128
#define BM 64
#define RS 72
#define FS 72

__global__ __launch_bounds__(256, 3)
void interp_kernel(const float* __restrict__ xyz_down,
                   const float* __restrict__ xyz_up,
                   const float* __restrict__ feat_down,
                   u16* __restrict__ interp_out)
{
    __shared__ u16   rbuf[TN * RS];
    __shared__ u16   ftbuf[DD * FS];
    __shared__ float xyzb[BM * 3];
    __shared__ float denp[TN * 2];
    __shared__ float invden[TN];

    const int tid = threadIdx.x;
    const int b  = blockIdx.x >> 7;
    const int n0 = (blockIdx.x & 127) * TN;

    const int nl_r = tid >> 1;
    const int half = tid & 1;
    const float* xu = xyz_up + (size_t)(b * NN + n0 + nl_r) * 3;
    const float ax = xu[0], ay = xu[1], az = xu[2];

    denp[tid] = 0.f;

    const int wave = tid >> 6;
    const int lane = tid & 63;
    const int q    = lane >> 4;
    const int nl   = lane & 15;

    f32x4 acc[2][4];
#pragma unroll
    for (int i = 0; i < 2; i++)
#pragma unroll
        for (int j = 0; j < 4; j++) acc[i][j] = (f32x4){0.f, 0.f, 0.f, 0.f};

    const int sm = (tid & 31) * 2;
    const int sd = (tid >> 5) * 8;

    for (int mc = 0; mc < MM; mc += BM) {
        __syncthreads();
        if (tid < 192) xyzb[tid] = xyz_down[(size_t)(b * MM + mc) * 3 + tid];
        {
            const float4* f0 = (const float4*)(feat_down + (size_t)(b * MM + mc + sm) * DD + sd);
            const float4* f1 = (const float4*)(feat_down + (size_t)(b * MM + mc + sm + 1) * DD + sd);
            float4 a0 = f0[0], a1 = f0[1];
            float4 b0 = f1[0], b1 = f1[1];
            float r0[8] = {a0.x, a0.y, a0.z, a0.w, a1.x, a1.y, a1.z, a1.w};
            float r1[8] = {b0.x, b0.y, b0.z, b0.w, b1.x, b1.y, b1.z, b1.w};
#pragma unroll
            for (int j = 0; j < 8; j++) {
                u32 pk = (u32)f2bf(r0[j]) | ((u32)f2bf(r1[j]) << 16);
                *(u32*)&ftbuf[(sd + j) * FS + sm] = pk;
            }
        }
        __syncthreads();
        {
            float dlc = 0.f;
#pragma unroll
            for (int s = 0; s < 4; s++) {
                bf16x8 v;
#pragma unroll
                for (int j = 0; j < 8; j++) {
                    int m = half * 32 + s * 8 + j;
                    float dx = ax - xyzb[3 * m + 0];
                    float dy = ay - xyzb[3 * m + 1];
                    float dz = az - xyzb[3 * m + 2];
                    float d = fmaf(dx, dx, fmaf(dy, dy, dz * dz)) + 1e-8f;
                    float r = __builtin_amdgcn_rcpf(d);
                    dlc += r;
                    v[j] = (short)f2bf(r);
                }
                *(bf16x8*)&rbuf[nl_r * RS + half * 32 + s * 8] = v;
            }
            denp[nl_r * 2 + half] += dlc;
        }
        __syncthreads();
        {
            const int rowbase = wave * 32;
#pragma unroll
            for (int k0 = 0; k0 < BM; k0 += 32) {
                bf16x8 a0 = *(bf16x8*)&rbuf[(rowbase + nl) * RS + k0 + q * 8];
                bf16x8 a1 = *(bf16x8*)&rbuf[(rowbase + 16 + nl) * RS + k0 + q * 8];
#pragma unroll
                for (int dt = 0; dt < 4; dt++) {
                    bf16x8 bb = *(bf16x8*)&ftbuf[(dt * 16 + nl) * FS + k0 + q * 8];
                    acc[0][dt] = __builtin_amdgcn_mfma_f32_16x16x32_bf16(a0, bb, acc[0][dt], 0, 0, 0);
                    acc[1][dt] = __builtin_amdgcn_mfma_f32_16x16x32_bf16(a1, bb, acc[1][dt], 0, 0, 0);
                }
            }
        }
    }

    __syncthreads();
    if (tid < TN) invden[tid] = 1.0f / (denp[tid * 2] + denp[tid * 2 + 1]);
    __syncthreads();
    {
        const int rowbase = wave * 32;
#pragma unroll
        for (int nt = 0; nt < 2; nt++) {
#pragma unroll
            for (int reg = 0; reg < 4; reg++) {
                int nloc = rowbase + nt * 16 + q * 4 + reg;
                float inv = invden[nloc];
                size_t gbase = (size_t)(b * NN + n0 + nloc) * DD;
#pragma unroll
                for (int dt = 0; dt < 4; dt++)
                    interp_out[gbase + dt * 16 + nl] = f2bf(acc[nt][dt][reg] * inv);
            }
        }
    }
}

#define T2 64

__global__ __launch_bounds__(256, 1)
void mlp_kernel(const float* __restrict__ feat_up,
                const u16*   __restrict__ interp,
                const float* __restrict__ W1, const float* __restrict__ b1,
                const float* __restrict__ g1, const float* __restrict__ be1,
                const float* __restrict__ m1, const float* __restrict__ v1,
                const float* __restrict__ W2, const float* __restrict__ b2,
                const float* __restrict__ g2, const float* __restrict__ be2,
                const float* __restrict__ m2, const float* __restrict__ v2,
                float* __restrict__ out)
{
    __shared__ u16 xb[T2 * 136];
    __shared__ u16 hb[T2 * 136];
    __shared__ u16 w1b[128 * 136];
    __shared__ u16 w2b[64 * 136];
    __shared__ float A1[128], Bc1[128], A2[64], Bc2[64];

    const int tid = threadIdx.x;
    const int b  = blockIdx.x >> 8;
    const int n0 = (blockIdx.x & 255) * T2;
    const int wave = tid >> 6;
    const int lane = tid & 63;
    const int q    = lane >> 4;
    const int nl   = lane & 15;

    if (tid < 128) {
        float a = g1[tid] * rsqrtf(v1[tid] + 1e-5f);
        A1[tid]  = a;
        Bc1[tid] = (b1[tid] - m1[tid]) * a + be1[tid];
    } else if (tid < 192) {
        int o = tid - 128;
        float a = g2[o] * rsqrtf(v2[o] + 1e-5f);
        A2[o]  = a;
        Bc2[o] = (b2[o] - m2[o]) * a + be2[o];
    }
    {
        const float4* src = (const float4*)(W1 + (size_t)(tid >> 1) * 128 + (tid & 1) * 64);
        u16* dst = &w1b[(tid >> 1) * 136 + (tid & 1) * 64];
#pragma unroll
        for (int i = 0; i < 8; i++)
            *(bf16x8*)(dst + 8 * i) = pack8(src[2 * i], src[2 * i + 1]);
    }
    {
        const float4* src = (const float4*)(W2 + (size_t)(tid >> 2) * 128 + (tid & 3) * 32);
        u16* dst = &w2b[(tid >> 2) * 136 + (tid & 3) * 32];
#pragma unroll
        for (int i = 0; i < 4; i++)
            *(bf16x8*)(dst + 8 * i) = pack8(src[2 * i], src[2 * i + 1]);
    }
    if (tid < 128) {
        int n = tid >> 1, hf = tid & 1;
        const float4* src = (const float4*)(feat_up + (size_t)(b * NN + n0 + n) * 64 + hf * 32);
        u16* dst = &xb[n * 136 + hf * 32];
#pragma unroll
        for (int i = 0; i < 4; i++)
            *(bf16x8*)(dst + 8 * i) = pack8(src[2 * i], src[2 * i + 1]);
    } else {
        int t2 = tid - 128;
        int n = t2 >> 1, hf = t2 & 1;
        const uint4* src = (const uint4*)(interp + (size_t)(b * NN + n0 + n) * 64 + hf * 32);
        u16* dst = &xb[n * 136 + 64 + hf * 32];
#pragma unroll
        for (int i = 0; i < 4; i++)
            *(uint4*)(dst + 8 * i) = src[i];
    }
    __syncthreads();

    f32x4 acc1[8];
#pragma unroll
    for (int i = 0; i < 8; i++) acc1[i] = (f32x4){0.f, 0.f, 0.f, 0.f};
#pragma unroll
    for (int k0 = 0; k0 < 128; k0 += 32) {
        bf16x8 a = *(bf16x8*)&xb[(wave * 16 + nl) * 136 + k0 + q * 8];
#pragma unroll
        for (int ot = 0; ot < 8; ot++) {
            bf16x8 bb = *(bf16x8*)&w1b[(ot * 16 + nl) * 136 + k0 + q * 8];
            acc1[ot] = __builtin_amdgcn_mfma_f32_16x16x32_bf16(a, bb, acc1[ot], 0, 0, 0);
        }
    }
#pragma unroll
    for (int ot = 0; ot < 8; ot++) {
        int o = ot * 16 + nl;
        float aa = A1[o], bc = Bc1[o];
#pragma unroll
        for (int reg = 0; reg < 4; reg++) {
            float v = fmaxf(fmaf(acc1[ot][reg], aa, bc), 0.f);
            hb[(wave * 16 + q * 4 + reg) * 136 + o] = f2bf(v);
        }
    }
    __syncthreads();

    f32x4 acc2[4];
#pragma unroll
    for (int i = 0; i < 4; i++) acc2[i] = (f32x4){0.f, 0.f, 0.f, 0.f};
#pragma unroll
    for (int k0 = 0; k0 < 128; k0 += 32) {
        bf16x8 a = *(bf16x8*)&hb[(wave * 16 + nl) * 136 + k0 + q * 8];
#pragma unroll
        for (int ot = 0; ot < 4; ot++) {
            bf16x8 bb = *(bf16x8*)&w2b[(ot * 16 + nl) * 136 + k0 + q * 8];
            acc2[ot] = __builtin_amdgcn_mfma_f32_16x16x32_bf16(a, bb, acc2[ot], 0, 0, 0);
        }
    }
#pragma unroll
    for (int ot = 0; ot < 4; ot++) {
        int o = ot * 16 + nl;
        float aa = A2[o], bc = Bc2[o];
#pragma unroll
        for (int reg = 0; reg < 4; reg++)
            out[(size_t)(b * NN + n0 + wave * 16 + q * 4 + reg) * 64 + o] =
                fmaf(acc2[ot][reg], aa, bc);
    }
}

extern "C" void kernel_launch(void* const* d_in, const int* in_sizes, int n_in,
                              void* d_out, int out_size, void* d_ws, size_t ws_size,
                              hipStream_t stream) {
    const float* xyz_down  = (const float*)d_in[0];
    const float* xyz_up    = (const float*)d_in[1];
    const float* feat_down = (const float*)d_in[2];
    const float* feat_up   = (const float*)d_in[3];
    const float* W1  = (const float*)d_in[4];
    const float* b1  = (const float*)d_in[5];
    const float* g1  = (const float*)d_in[6];
    const float* be1 = (const float*)d_in[7];
    const float* m1  = (const float*)d_in[8];
    const float* v1  = (const float*)d_in[9];
    const float* W2  = (const float*)d_in[10];
    const float* b2  = (const float*)d_in[11];
    const float* g2  = (const float*)d_in[12];
    const float* be2 = (const float*)d_in[13];
    const float* m2  = (const float*)d_in[14];
    const float* v2  = (const float*)d_in[15];
    float* out = (float*)d_out;
    char* ws = (char*)d_ws;

    if (ws_size >= WS_NEED) {
        u16*    interp = (u16*)(ws + OFF_INTERP);
        u16*    fdT    = (u16*)(ws + OFF_FDT);
        float4* xyzd2  = (float4*)(ws + OFF_XYZ);
        u16*    w1bf   = (u16*)(ws + OFF_W1);
        u16*    w2bf   = (u16*)(ws + OFF_W2);
        float*  bnbuf  = (float*)(ws + OFF_BN);

        prep_kernel<<<dim3(67), dim3(256), 0, stream>>>(
            xyz_down, feat_down, W1, b1, g1, be1, m1, v1,
            W2, b2, g2, be2, m2, v2, fdT, xyzd2, w1bf, w2bf, bnbuf);
        interp2_kernel<<<dim3(BB * (NN / 64)), dim3(256), 0, stream>>>(
            xyz_up, fdT, xyzd2, interp);
        mlp2_kernel<<<dim3(BB * (NN / 64)), dim3(256), 0, stream>>>(
            feat_up, interp, w1bf, w2bf, bnbuf, out);
    } else {
        u16* interp = (u16*)d_ws;
        interp_kernel<<<dim3(BB * (NN / TN)), dim3(256), 0, stream>>>(
            xyz_down, xyz_up, feat_down, interp);
        mlp_kernel<<<dim3(BB * (NN / T2)), dim3(256), 0, stream>>>(
            feat_up, interp, W1, b1, g1, be1, m1, v1,
            W2, b2, g2, be2, m2, v2, out);
    }
}